// Round 3
// baseline (399.311 us; speedup 1.0000x reference)
//
#include <hip/hip_runtime.h>

#define BN 32768
#define IN 512
#define NE 8
#define NH 128
#define MO 256
#define RT 64    // rows per expert tile
#define KC1 64   // stage-1 k-chunk
#define KC2 16   // stage-2 k-chunk

// ---------------- gating: one row per lane; f64 accumulation ----------------
// f64 so top-2 ranking matches the f64-ish np reference at near-ties (an f32
// rank flip injects ~1e-2 absmax). wg reads are wave-uniform -> s_load.
__global__ __launch_bounds__(64) void gate_kernel(
    const float* __restrict__ x, const float* __restrict__ wg,
    int* __restrict__ gcount, int* __restrict__ gload, float* __restrict__ gimp,
    int* __restrict__ idx_list, float* __restrict__ gate_list,
    float* __restrict__ out, const float* __restrict__ bout)
{
    __shared__ int counts_s[NE];
    __shared__ int load_s[NE];
    __shared__ float imp_s[NE];
    __shared__ int base_s[NE];
    __shared__ int rec_e[128];
    __shared__ int rec_p[128];
    __shared__ float rec_g[128];

    int tid = threadIdx.x;
    if (tid < NE) { counts_s[tid] = 0; load_s[tid] = 0; imp_s[tid] = 0.f; }
    __syncthreads();

    int row = blockIdx.x * 64 + tid;
    const float* xr = x + (size_t)row * IN;

    double acc[NE];
    #pragma unroll
    for (int e = 0; e < NE; ++e) acc[e] = 0.0;

    for (int k = 0; k < IN; k += 4) {
        float4 xv = *(const float4*)(xr + k);
        const float* wk = wg + k * NE;   // uniform across lanes -> scalar loads
        float xa[4] = {xv.x, xv.y, xv.z, xv.w};
        #pragma unroll
        for (int j = 0; j < 4; ++j) {
            double xd = (double)xa[j];
            #pragma unroll
            for (int e = 0; e < NE; ++e)
                acc[e] += xd * (double)wk[j * NE + e];
        }
    }

    // fused out-init
    float2 bo = *(const float2*)bout;
    *(float2*)(out + (size_t)row * 2) = bo;

    int e0 = 0; double v0 = acc[0];
    #pragma unroll
    for (int e = 1; e < NE; ++e) if (acc[e] > v0) { v0 = acc[e]; e0 = e; }
    int e1 = (e0 == 0) ? 1 : 0; double v1 = acc[e1];
    #pragma unroll
    for (int e = 0; e < NE; ++e)
        if (e != e0 && acc[e] > v1) { v1 = acc[e]; e1 = e; }

    float t1 = expf((float)(v1 - v0));
    float s = 1.f + t1;
    float g0 = 1.f / s;
    float g1 = t1 / s;

    atomicAdd(&imp_s[e0], g0);
    atomicAdd(&imp_s[e1], g1);
    if (g0 > 0.f) atomicAdd(&load_s[e0], 1);
    if (g1 > 0.f) atomicAdd(&load_s[e1], 1);
    int p0 = atomicAdd(&counts_s[e0], 1);
    int p1 = atomicAdd(&counts_s[e1], 1);
    rec_e[tid * 2] = e0; rec_e[tid * 2 + 1] = e1;
    rec_g[tid * 2] = g0; rec_g[tid * 2 + 1] = g1;
    rec_p[tid * 2] = p0; rec_p[tid * 2 + 1] = p1;
    __syncthreads();

    if (tid < NE) {
        base_s[tid] = atomicAdd(&gcount[tid], counts_s[tid]);
        atomicAdd(&gimp[tid], imp_s[tid]);
        atomicAdd(&gload[tid], load_s[tid]);
    }
    __syncthreads();

    #pragma unroll
    for (int q = 0; q < 2; ++q) {
        int eq = rec_e[tid * 2 + q];
        int pos = base_s[eq] + rec_p[tid * 2 + q];
        idx_list[eq * BN + pos] = row;
        gate_list[eq * BN + pos] = rec_g[tid * 2 + q];
    }
}

// ---------------- loss ----------------
__global__ void loss_kernel(const float* __restrict__ gimp, const int* __restrict__ gload,
                            float* __restrict__ out) {
    if (threadIdx.x == 0 && blockIdx.x == 0) {
        float mi = 0.f, ml = 0.f;
        for (int e = 0; e < NE; ++e) { mi += gimp[e]; ml += (float)gload[e]; }
        mi *= 0.125f; ml *= 0.125f;
        float vi = 0.f, vl = 0.f;
        for (int e = 0; e < NE; ++e) {
            float d = gimp[e] - mi;  vi += d * d;
            float d2 = (float)gload[e] - ml; vl += d2 * d2;
        }
        vi *= (1.f / 7.f); vl *= (1.f / 7.f);
        float loss = (vi / (mi * mi + 1e-10f) + vl / (ml * ml + 1e-10f)) * 0.01f;
        out[BN * 2] = loss;
    }
}

// ---------------- expert compute: 64-row tile, 512 threads ----------------
// Register-prefetch pipeline: plain global loads for chunk c+1 issue before
// computing chunk c; barriers don't drain register loads, so L2 latency is
// hidden under ~2000 cyc of FMA. LDS 48KB union, all layouts row-major,
// A-frags read along k (broadcast), B-frags the measured-conflict-free
// b128 pattern.
__global__ __launch_bounds__(512, 4) void expert_kernel(
    const float* __restrict__ x,
    const float* __restrict__ W1, const float* __restrict__ b1,
    const float* __restrict__ W2, const float* __restrict__ b2,
    const float* __restrict__ Wout,
    const int* __restrict__ gcount,
    const int* __restrict__ idx_list, const float* __restrict__ gate_list,
    float* __restrict__ out)
{
    __shared__ __align__(16) union {
        struct { float xs[RT][KC1]; float ws1[KC1][NH]; } s1;  // 16K + 32K
        struct { float hs[RT][NH];  float w2s[KC2][MO]; } s2;  // 32K + 16K
    } sm;

    int e = blockIdx.y;
    int cnt = gcount[e];
    int row0 = blockIdx.x * RT;
    if (row0 >= cnt) return;
    int tid = threadIdx.x;
    int tx = tid & 31;   // col group
    int ty = tid >> 5;   // 0..15 -> rows ty*4..+3

    // X staging: 8 threads per row, 2 float4 each
    int xr = tid >> 3, xf = tid & 7;
    int sgi = row0 + xr; if (sgi >= cnt) sgi = cnt - 1;
    const float* xrow = x + (size_t)idx_list[e * BN + sgi] * IN;

    const float* W1e = W1 + (size_t)e * IN * NH;
    const float* W2e = W2 + (size_t)e * NH * MO;

    // ---- stage 1: H[64x128] = relu(X @ W1 + b1) ----
    float c1[4][4] = {};
    float4 px0 = *(const float4*)(xrow + xf * 4);
    float4 px1 = *(const float4*)(xrow + 32 + xf * 4);
    float4 pw[4];
    #pragma unroll
    for (int p = 0; p < 4; ++p)
        pw[p] = *(const float4*)(W1e + p * 2048 + tid * 4);

    for (int c = 0; c < IN / KC1; ++c) {
        if (c) __syncthreads();               // prev chunk fully consumed
        *(float4*)&sm.s1.xs[xr][xf * 4]      = px0;
        *(float4*)&sm.s1.xs[xr][32 + xf * 4] = px1;
        {
            float* w1l = &sm.s1.ws1[0][0];
            #pragma unroll
            for (int p = 0; p < 4; ++p)
                *(float4*)(w1l + p * 2048 + tid * 4) = pw[p];
        }
        __syncthreads();                      // publish chunk c
        if (c < IN / KC1 - 1) {               // prefetch c+1 (overlaps compute)
            int k1 = (c + 1) * KC1;
            px0 = *(const float4*)(xrow + k1 + xf * 4);
            px1 = *(const float4*)(xrow + k1 + 32 + xf * 4);
            #pragma unroll
            for (int p = 0; p < 4; ++p)
                pw[p] = *(const float4*)(W1e + (size_t)k1 * NH + p * 2048 + tid * 4);
        }
        #pragma unroll
        for (int q4 = 0; q4 < KC1 / 4; ++q4) {
            float a[4][4], b[4][4];
            #pragma unroll
            for (int i = 0; i < 4; ++i) {
                float4 av = *(const float4*)&sm.s1.xs[ty * 4 + i][q4 * 4];
                a[i][0] = av.x; a[i][1] = av.y; a[i][2] = av.z; a[i][3] = av.w;
            }
            #pragma unroll
            for (int q = 0; q < 4; ++q) {
                float4 bv = *(const float4*)&sm.s1.ws1[q4 * 4 + q][tx * 4];
                b[q][0] = bv.x; b[q][1] = bv.y; b[q][2] = bv.z; b[q][3] = bv.w;
            }
            #pragma unroll
            for (int q = 0; q < 4; ++q)
                #pragma unroll
                for (int i = 0; i < 4; ++i)
                    #pragma unroll
                    for (int j = 0; j < 4; ++j)
                        c1[i][j] = fmaf(a[i][q], b[q][j], c1[i][j]);
        }
    }

    // prefetch W2 chunk 0 — overlaps relu/hs-store/barrier
    float4 pw2[2];
    #pragma unroll
    for (int p = 0; p < 2; ++p)
        pw2[p] = *(const float4*)(W2e + p * 2048 + tid * 4);

    __syncthreads();                          // stage-1 LDS reads done
    {
        float4 bv = *(const float4*)(b1 + e * NH + tx * 4);
        float bb[4] = {bv.x, bv.y, bv.z, bv.w};
        #pragma unroll
        for (int i = 0; i < 4; ++i) {
            float4 h;
            h.x = fmaxf(c1[i][0] + bb[0], 0.f);
            h.y = fmaxf(c1[i][1] + bb[1], 0.f);
            h.z = fmaxf(c1[i][2] + bb[2], 0.f);
            h.w = fmaxf(c1[i][3] + bb[3], 0.f);
            *(float4*)&sm.s2.hs[ty * 4 + i][tx * 4] = h;
        }
    }

    // ---- stage 2: Z[64x256] = H @ W2 ----
    float z[4][8] = {};
    for (int c = 0; c < NH / KC2; ++c) {
        int k0 = c * KC2;
        if (c) __syncthreads();
        {
            float* w2l = &sm.s2.w2s[0][0];
            *(float4*)(w2l + tid * 4)        = pw2[0];
            *(float4*)(w2l + 2048 + tid * 4) = pw2[1];
        }
        __syncthreads();                      // publish hs (c==0) + w2s
        if (c < NH / KC2 - 1) {
            #pragma unroll
            for (int p = 0; p < 2; ++p)
                pw2[p] = *(const float4*)(W2e + (size_t)(k0 + KC2) * MO + p * 2048 + tid * 4);
        }
        #pragma unroll
        for (int q4 = 0; q4 < KC2 / 4; ++q4) {
            float a[4][4];
            #pragma unroll
            for (int i = 0; i < 4; ++i) {
                float4 av = *(const float4*)&sm.s2.hs[ty * 4 + i][k0 + q4 * 4];
                a[i][0] = av.x; a[i][1] = av.y; a[i][2] = av.z; a[i][3] = av.w;
            }
            #pragma unroll
            for (int q = 0; q < 4; ++q) {
                float4 blo = *(const float4*)&sm.s2.w2s[q4 * 4 + q][tx * 4];
                float4 bhi = *(const float4*)&sm.s2.w2s[q4 * 4 + q][128 + tx * 4];
                float bl[4] = {blo.x, blo.y, blo.z, blo.w};
                float bh[4] = {bhi.x, bhi.y, bhi.z, bhi.w};
                #pragma unroll
                for (int i = 0; i < 4; ++i)
                    #pragma unroll
                    for (int j = 0; j < 4; ++j) {
                        z[i][j]     = fmaf(a[i][q], bl[j], z[i][j]);
                        z[i][j + 4] = fmaf(a[i][q], bh[j], z[i][j + 4]);
                    }
            }
        }
    }

    // ---- epilogue: softmax over 256 cols (32 lanes x 8), fused @Wout ----
    float4 b2a = *(const float4*)(b2 + e * MO + tx * 4);
    float4 b2b = *(const float4*)(b2 + e * MO + 128 + tx * 4);
    float bz[8] = {b2a.x, b2a.y, b2a.z, b2a.w, b2b.x, b2b.y, b2b.z, b2b.w};
    float4 wa0 = *(const float4*)(Wout + tx * 8);
    float4 wa1 = *(const float4*)(Wout + tx * 8 + 4);
    float4 wb0 = *(const float4*)(Wout + 256 + tx * 8);
    float4 wb1 = *(const float4*)(Wout + 256 + tx * 8 + 4);
    float wo0[8] = {wa0.x, wa0.z, wa1.x, wa1.z, wb0.x, wb0.z, wb1.x, wb1.z};
    float wo1[8] = {wa0.y, wa0.w, wa1.y, wa1.w, wb0.y, wb0.w, wb1.y, wb1.w};

    #pragma unroll
    for (int i = 0; i < 4; ++i) {
        float m = -1e30f;
        #pragma unroll
        for (int j = 0; j < 8; ++j) { z[i][j] += bz[j]; m = fmaxf(m, z[i][j]); }
        #pragma unroll
        for (int mk = 1; mk < 32; mk <<= 1) m = fmaxf(m, __shfl_xor(m, mk, 64));
        float s = 0.f, w0 = 0.f, w1 = 0.f;
        #pragma unroll
        for (int j = 0; j < 8; ++j) {
            float t = __expf(z[i][j] - m);
            s += t;
            w0 = fmaf(t, wo0[j], w0);
            w1 = fmaf(t, wo1[j], w1);
        }
        #pragma unroll
        for (int mk = 1; mk < 32; mk <<= 1) {
            s  += __shfl_xor(s,  mk, 64);
            w0 += __shfl_xor(w0, mk, 64);
            w1 += __shfl_xor(w1, mk, 64);
        }
        if (tx == 0) {
            int gi = row0 + ty * 4 + i;
            if (gi < cnt) {
                float g = gate_list[e * BN + gi];
                int brow = idx_list[e * BN + gi];
                float inv = 1.f / s;
                atomicAdd(&out[brow * 2 + 0], g * w0 * inv);
                atomicAdd(&out[brow * 2 + 1], g * w1 * inv);
            }
        }
    }
}

extern "C" void kernel_launch(void* const* d_in, const int* in_sizes, int n_in,
                              void* d_out, int out_size, void* d_ws, size_t ws_size,
                              hipStream_t stream) {
    const float* x    = (const float*)d_in[0];
    // d_in[1] = cat_prop, unused by the reference
    const float* wg   = (const float*)d_in[2];
    const float* W1   = (const float*)d_in[3];
    const float* b1   = (const float*)d_in[4];
    const float* W2   = (const float*)d_in[5];
    const float* b2   = (const float*)d_in[6];
    const float* Wout = (const float*)d_in[7];
    const float* bout = (const float*)d_in[8];
    float* out = (float*)d_out;

    char* ws = (char*)d_ws;
    int*   gcount    = (int*)(ws + 0);
    int*   gload     = (int*)(ws + 32);
    float* gimp      = (float*)(ws + 64);
    int*   idx_list  = (int*)(ws + 128);
    float* gate_list = (float*)(ws + 128 + sizeof(int) * NE * BN);

    hipMemsetAsync(ws, 0, 128, stream);
    gate_kernel<<<BN / 64, 64, 0, stream>>>(x, wg, gcount, gload, gimp,
                                            idx_list, gate_list, out, bout);
    loss_kernel<<<1, 64, 0, stream>>>(gimp, gload, out);
    dim3 eg(BN / RT, NE);
    expert_kernel<<<eg, 512, 0, stream>>>(x, W1, b1, W2, b2, Wout,
                                          gcount, idx_list, gate_list, out);
}